// Round 3
// baseline (365.356 us; speedup 1.0000x reference)
//
#include <hip/hip_runtime.h>
#include <math.h>

namespace {

constexpr int DD = 128;
constexpr int DM = 127;
constexpr int D3 = DD * DD * DD;

struct Consts {
  float kn, ps, eta, dtpm, grav;
  float lo_hi;   // 1.5*PS
  float hi_th;   // D*CELL - 0.5*PS - CELL
  float dcell;   // D*CELL
  float cell;    // CELL
  float hps;     // 0.5*PS
};

__device__ inline float bforce(float p, float v, float mkv, const Consts& c) {
  float lo = ((p > c.ps) && (p < c.lo_hi)) ? mkv : 0.0f;
  float hi = (p > c.hi_th) ? mkv : 0.0f;
  float t = ((p - c.dcell) + c.cell) + c.hps;   // mirrors ref op order
  return c.kn * lo * (c.lo_hi - p) - c.kn * hi * t - c.eta * v * lo - c.eta * v * hi;
}

// Scalar fallback (R=2, full 125-offset correctness path; rarely taken).
template <int R>
__device__ void collide(int x, int y, int z,
                        const float* __restrict__ xg, const float* __restrict__ yg,
                        const float* __restrict__ zg,
                        const float* __restrict__ v0x, const float* __restrict__ v0y,
                        const float* __restrict__ v0z,
                        const float* __restrict__ v1x, const float* __restrict__ v1y,
                        const float* __restrict__ v1z,
                        float xn, float yn, float zn,
                        float vxn, float vyn, float vzn,
                        float& fx, float& fy, float& fz, const Consts& c) {
  int xw[2 * R + 1];
#pragma unroll
  for (int ox = -R; ox <= R; ++ox) xw[ox + R] = (x + ox) & DM;

  for (int oz = -R; oz <= R; ++oz) {
    const int zr = (z + oz) & DM;
    for (int oy = -R; oy <= R; ++oy) {
      const int yr = (y + oy) & DM;
      const int rb = (zr * DD + yr) * DD;
#pragma unroll
      for (int m = 0; m < 2; ++m) {
        const float* __restrict__ PX = xg + m * D3 + rb;
        const float* __restrict__ PY = yg + m * D3 + rb;
        const float* __restrict__ PZ = zg + m * D3 + rb;
        const float* __restrict__ VX = (m == 0 ? v0x : v1x) + rb;
        const float* __restrict__ VY = (m == 0 ? v0y : v1y) + rb;
        const float* __restrict__ VZ = (m == 0 ? v0z : v1z) + rb;
#pragma unroll
        for (int ox = -R; ox <= R; ++ox) {
          const int xi = xw[ox + R];
          float dx = xn - PX[xi];
          float dy = yn - PY[xi];
          float dz = zn - PZ[xi];
          float d2 = fmaf(dx, dx, fmaf(dy, dy, dz * dz));
          float d2c = fmaxf(d2, 1e-12f);
          float r = __builtin_amdgcn_rsqf(d2c);
          float dist = d2c * r;
          float inv = fminf(r, 1.0e4f);
          float dvx = vxn - VX[xi];
          float dvy = vyn - VY[xi];
          float dvz = vzn - VZ[xi];
          float dvn = fmaf(dvx, dx, fmaf(dvy, dy, dvz * dz)) * inv;
          float coef = (dist < c.ps) ? (fmaf(c.kn, dist - c.ps, c.eta * dvn) * inv) : 0.0f;
          fx = fmaf(coef, dx, fx);
          fy = fmaf(coef, dy, fy);
          fz = fmaf(coef, dz, fz);
        }
      }
    }
  }
}

__global__ void __launch_bounds__(256)
checker(const float* __restrict__ xg, const float* __restrict__ yg,
        const float* __restrict__ zg, unsigned* flag, float cell) {
  int i = blockIdx.x * 256 + threadIdx.x;   // i in [0, 2*D3)
  int ix = i & DM;
  int iy = (i >> 7) & DM;
  int iz = (i >> 14) & DM;
  float jx = xg[i] - ix * cell;
  float jy = yg[i] - iy * cell;
  float jz = zg[i] - iz * cell;
  const float lo = -1e-5f, hi = cell + 1e-5f;
  bool bad = (jx < lo) | (jx > hi) | (jy < lo) | (jy > hi) | (jz < lo) | (jz > hi);
  if (bad) atomicOr(flag, 1u);
}

// 4 x-cells/thread; 18 (oz,oy,m) row-iters fully unrolled with double-buffered
// float4 prefetch; halos via __shfl from neighbor lanes (x is periodic and one
// wave-half covers a full x-row); XCD-chunked 1D block swizzle for L2 locality.
__global__ void __launch_bounds__(256)
dem_pass(int n,
         const float* __restrict__ xg, const float* __restrict__ yg,
         const float* __restrict__ zg,
         const float* __restrict__ v0x, const float* __restrict__ v0y,
         const float* __restrict__ v0z,
         const float* __restrict__ v1x, const float* __restrict__ v1y,
         const float* __restrict__ v1z,
         const float* __restrict__ vnx, const float* __restrict__ vny,
         const float* __restrict__ vnz,
         const float* __restrict__ maskn,
         float* __restrict__ outx, float* __restrict__ outy, float* __restrict__ outz,
         const unsigned* __restrict__ flag, Consts cc) {
  const int t = threadIdx.x;
  const int tx = t & 31;
  const int ty = t >> 5;                       // 0..7
  // bijective chunked XCD swizzle: 2048 wgs, 8 XCDs, 256 wgs (16 z-slices) each
  const int wg = blockIdx.x;
  const int id = ((wg & 7) << 8) | (wg >> 3);
  const int z = id >> 4;                       // 0..127
  const int y = ((id & 15) << 3) | ty;         // 0..127
  const int x0 = tx << 2;
  const int idx = (z * DD + y) * DD + x0;
  const int nn = n * D3;

  const float4 xc4 = *(const float4*)(xg + nn + idx);
  const float4 yc4 = *(const float4*)(yg + nn + idx);
  const float4 zc4 = *(const float4*)(zg + nn + idx);
  const float4 vx4 = *(const float4*)(vnx + idx);
  const float4 vy4 = *(const float4*)(vny + idx);
  const float4 vz4 = *(const float4*)(vnz + idx);
  const float4 mk4 = *(const float4*)(maskn + idx);

  float pxc[4] = {xc4.x, xc4.y, xc4.z, xc4.w};
  float pyc[4] = {yc4.x, yc4.y, yc4.z, yc4.w};
  float pzc[4] = {zc4.x, zc4.y, zc4.z, zc4.w};
  float vxc[4] = {vx4.x, vx4.y, vx4.z, vx4.w};
  float vyc[4] = {vy4.x, vy4.y, vy4.z, vy4.w};
  float vzc[4] = {vz4.x, vz4.y, vz4.z, vz4.w};
  float mkc[4] = {mk4.x, mk4.y, mk4.z, mk4.w};

  float fxA[4] = {0.f, 0.f, 0.f, 0.f};
  float fyA[4] = {0.f, 0.f, 0.f, 0.f};
  float fzA[4] = {0.f, 0.f, 0.f, 0.f};

  if (*flag == 0u) {
    const int laneL = (t & 32) | ((tx + 31) & 31);
    const int laneR = (t & 32) | ((tx + 1) & 31);
    const int zr[3] = {(z + DM) & DM, z, (z + 1) & DM};
    const int yr[3] = {(y + DM) & DM, y, (y + 1) & DM};
    const float* __restrict__ P[2][6] = {
        {xg, yg, zg, v0x, v0y, v0z},
        {xg + D3, yg + D3, zg + D3, v1x, v1y, v1z}};

    float4 buf[2][6];
    {
      const int rb = (zr[0] * DD + yr[0]) * DD + x0;
#pragma unroll
      for (int f = 0; f < 6; ++f) buf[0][f] = *(const float4*)(P[0][f] + rb);
    }

#pragma unroll
    for (int k = 0; k < 18; ++k) {
      const int cur = k & 1;
      const int nxt = cur ^ 1;
      if (k + 1 < 18) {                        // prefetch next row
        const int k1 = k + 1;
        const int m1 = k1 & 1;
        const int r1 = k1 >> 1;
        const int rb = (zr[r1 / 3] * DD + yr[r1 % 3]) * DD + x0;
#pragma unroll
        for (int f = 0; f < 6; ++f) buf[nxt][f] = *(const float4*)(P[m1][f] + rb);
      }
      // expand 6-wide x-window per field: halos from neighbor lanes
      float w[6][6];
#pragma unroll
      for (int f = 0; f < 6; ++f) {
        float4 b = buf[cur][f];
        w[f][0] = __shfl(b.w, laneL, 64);
        w[f][1] = b.x;
        w[f][2] = b.y;
        w[f][3] = b.z;
        w[f][4] = b.w;
        w[f][5] = __shfl(b.x, laneR, 64);
      }
#pragma unroll
      for (int i = 0; i < 4; ++i) {
#pragma unroll
        for (int ox = 0; ox < 3; ++ox) {
          const int u = i + ox;
          float dx = pxc[i] - w[0][u];
          float dy = pyc[i] - w[1][u];
          float dz = pzc[i] - w[2][u];
          float d2 = fmaf(dx, dx, fmaf(dy, dy, dz * dz));
          float d2c = fmaxf(d2, 1e-12f);
          float r = __builtin_amdgcn_rsqf(d2c);
          float dist = d2c * r;
          float inv = fminf(r, 1.0e4f);
          float dvx = vxc[i] - w[3][u];
          float dvy = vyc[i] - w[4][u];
          float dvz = vzc[i] - w[5][u];
          float dvn = fmaf(dvx, dx, fmaf(dvy, dy, dvz * dz)) * inv;
          float coef = (dist < cc.ps) ? (fmaf(cc.kn, dist - cc.ps, cc.eta * dvn) * inv) : 0.0f;
          fxA[i] = fmaf(coef, dx, fxA[i]);
          fyA[i] = fmaf(coef, dy, fyA[i]);
          fzA[i] = fmaf(coef, dz, fzA[i]);
        }
      }
    }
  } else {
#pragma unroll
    for (int i = 0; i < 4; ++i) {
      collide<2>(x0 + i, y, z, xg, yg, zg, v0x, v0y, v0z, v1x, v1y, v1z,
                 pxc[i], pyc[i], pzc[i], vxc[i], vyc[i], vzc[i],
                 fxA[i], fyA[i], fzA[i], cc);
    }
  }

  float4 ox4, oy4, oz4;
#pragma unroll
  for (int i = 0; i < 4; ++i) {
    const float fxb = bforce(pxc[i], vxc[i], mkc[i], cc);
    const float fyb = bforce(pyc[i], vyc[i], mkc[i], cc);
    const float fzb = bforce(pzc[i], vzc[i], mkc[i], cc);
    const float s = cc.dtpm * mkc[i];
    (&ox4.x)[i] = vxc[i] + s * (fxb - fxA[i]);
    (&oy4.x)[i] = vyc[i] + s * (fyb - fyA[i]);
    (&oz4.x)[i] = vzc[i] + s * ((cc.grav - fzA[i]) + fzb);
  }
  *(float4*)(outx + idx) = ox4;
  *(float4*)(outy + idx) = oy4;
  *(float4*)(outz + idx) = oz4;
}

}  // namespace

extern "C" void kernel_launch(void* const* d_in, const int* in_sizes, int n_in,
                              void* d_out, int out_size, void* d_ws, size_t ws_size,
                              hipStream_t stream) {
  const float* xg = (const float*)d_in[0];
  const float* yg = (const float*)d_in[1];
  const float* zg = (const float*)d_in[2];
  const float* vx = (const float*)d_in[3];
  const float* vy = (const float*)d_in[4];
  const float* vz = (const float*)d_in[5];
  const float* mk = (const float*)d_in[6];
  float* out = (float*)d_out;
  unsigned* flag = (unsigned*)d_ws;

  const double PSd = 0.1, CELLd = 0.1, KNd = 6.0e6;
  const double ALPHA = -log(0.5) / 3.141592653589793;
  const double GAMMA = ALPHA / sqrt(ALPHA * ALPHA + 1.0);
  const double PMd = 4.0 / 3.0 * 3.1415 * (0.1 * 0.1 * 0.1) * 2700.0;
  const double ETAd = 2.0 * GAMMA * sqrt(KNd * PMd);

  Consts cc;
  cc.kn = (float)KNd;
  cc.ps = (float)PSd;
  cc.eta = (float)ETAd;
  cc.dtpm = (float)(1e-4 / PMd);
  cc.grav = (float)(-9.8 * PMd);
  cc.lo_hi = (float)(1.5 * PSd);
  cc.hi_th = (float)(DD * CELLd - 0.5 * PSd - CELLd);
  cc.dcell = (float)(DD * CELLd);
  cc.cell = (float)CELLd;
  cc.hps = (float)(0.5 * PSd);

  hipMemsetAsync(d_ws, 0, sizeof(unsigned), stream);
  checker<<<(2 * D3) / 256, 256, 0, stream>>>(xg, yg, zg, flag, cc.cell);

  dim3 blk(256, 1, 1), grd(2048, 1, 1);
  // Pass n=0: neighbor velocities = original inputs (both layers); own = input layer 0.
  dem_pass<<<grd, blk, 0, stream>>>(
      0, xg, yg, zg,
      vx, vy, vz,
      vx + D3, vy + D3, vz + D3,
      vx, vy, vz,
      mk,
      out, out + 2 * D3, out + 4 * D3,
      flag, cc);
  // Pass n=1: m=0 source is the UPDATED layer 0 (just written to out).
  dem_pass<<<grd, blk, 0, stream>>>(
      1, xg, yg, zg,
      out, out + 2 * D3, out + 4 * D3,
      vx + D3, vy + D3, vz + D3,
      vx + D3, vy + D3, vz + D3,
      mk + D3,
      out + D3, out + 3 * D3, out + 5 * D3,
      flag, cc);
}

// Round 4
// 187.887 us; speedup vs baseline: 1.9446x; 1.9446x over previous
//
#include <hip/hip_runtime.h>
#include <math.h>

namespace {

constexpr int DD = 128;
constexpr int DM = 127;
constexpr int D3 = DD * DD * DD;

struct Consts {
  float kn, ps, eta, dtpm, grav;
  float lo_hi;   // 1.5*PS
  float hi_th;   // D*CELL - 0.5*PS - CELL
  float dcell;   // D*CELL
  float cell;    // CELL
  float hps;     // 0.5*PS
};

__device__ inline float bforce(float p, float v, float mkv, const Consts& c) {
  float lo = ((p > c.ps) && (p < c.lo_hi)) ? mkv : 0.0f;
  float hi = (p > c.hi_th) ? mkv : 0.0f;
  float t = ((p - c.dcell) + c.cell) + c.hps;   // mirrors ref op order
  return c.kn * lo * (c.lo_hi - p) - c.kn * hi * t - c.eta * v * lo - c.eta * v * hi;
}

__device__ __forceinline__ float f4c(const float4& v, int u) {
  return u == 0 ? v.x : (u == 1 ? v.y : (u == 2 ? v.z : v.w));
}

// Scalar fallback (R=2, full 125-offset correctness path; rarely taken).
template <int R>
__device__ void collide(int x, int y, int z,
                        const float* __restrict__ xg, const float* __restrict__ yg,
                        const float* __restrict__ zg,
                        const float* __restrict__ v0x, const float* __restrict__ v0y,
                        const float* __restrict__ v0z,
                        const float* __restrict__ v1x, const float* __restrict__ v1y,
                        const float* __restrict__ v1z,
                        float xn, float yn, float zn,
                        float vxn, float vyn, float vzn,
                        float& fx, float& fy, float& fz, const Consts& c) {
  int xw[2 * R + 1];
#pragma unroll
  for (int ox = -R; ox <= R; ++ox) xw[ox + R] = (x + ox) & DM;

  for (int oz = -R; oz <= R; ++oz) {
    const int zr = (z + oz) & DM;
    for (int oy = -R; oy <= R; ++oy) {
      const int yr = (y + oy) & DM;
      const int rb = (zr * DD + yr) * DD;
#pragma unroll
      for (int m = 0; m < 2; ++m) {
        const float* __restrict__ PX = xg + m * D3 + rb;
        const float* __restrict__ PY = yg + m * D3 + rb;
        const float* __restrict__ PZ = zg + m * D3 + rb;
        const float* __restrict__ VX = (m == 0 ? v0x : v1x) + rb;
        const float* __restrict__ VY = (m == 0 ? v0y : v1y) + rb;
        const float* __restrict__ VZ = (m == 0 ? v0z : v1z) + rb;
#pragma unroll
        for (int ox = -R; ox <= R; ++ox) {
          const int xi = xw[ox + R];
          float dx = xn - PX[xi];
          float dy = yn - PY[xi];
          float dz = zn - PZ[xi];
          float d2 = fmaf(dx, dx, fmaf(dy, dy, dz * dz));
          float d2c = fmaxf(d2, 1e-12f);
          float r = __builtin_amdgcn_rsqf(d2c);
          float dist = d2c * r;
          float inv = fminf(r, 1.0e4f);
          float dvx = vxn - VX[xi];
          float dvy = vyn - VY[xi];
          float dvz = vzn - VZ[xi];
          float dvn = fmaf(dvx, dx, fmaf(dvy, dy, dvz * dz)) * inv;
          float coef = (dist < c.ps) ? (fmaf(c.kn, dist - c.ps, c.eta * dvn) * inv) : 0.0f;
          fx = fmaf(coef, dx, fx);
          fy = fmaf(coef, dy, fy);
          fz = fmaf(coef, dz, fz);
        }
      }
    }
  }
}

__global__ void __launch_bounds__(256)
checker(const float* __restrict__ xg, const float* __restrict__ yg,
        const float* __restrict__ zg, unsigned* flag, float cell) {
  int i = blockIdx.x * 256 + threadIdx.x;   // i in [0, 2*D3)
  int ix = i & DM;
  int iy = (i >> 7) & DM;
  int iz = (i >> 14) & DM;
  float jx = xg[i] - ix * cell;
  float jy = yg[i] - iy * cell;
  float jz = zg[i] - iz * cell;
  const float lo = -1e-5f, hi = cell + 1e-5f;
  bool bad = (jx < lo) | (jx > hi) | (jy < lo) | (jy > hi) | (jz < lo) | (jz > hi);
  if (bad) atomicOr(flag, 1u);
}

// 4 x-cells/thread; rolled loop over 9 (oz,oy) pairs with two named row-buffers
// (A = layer0 rows, B = layer1 rows) in a depth-1 software pipeline; x-halos via
// __shfl; XCD-chunked 1D block swizzle for L2 locality.
__global__ void __launch_bounds__(256)
dem_pass(int n,
         const float* __restrict__ xg, const float* __restrict__ yg,
         const float* __restrict__ zg,
         const float* __restrict__ v0x, const float* __restrict__ v0y,
         const float* __restrict__ v0z,
         const float* __restrict__ v1x, const float* __restrict__ v1y,
         const float* __restrict__ v1z,
         const float* __restrict__ vnx, const float* __restrict__ vny,
         const float* __restrict__ vnz,
         const float* __restrict__ maskn,
         float* __restrict__ outx, float* __restrict__ outy, float* __restrict__ outz,
         const unsigned* __restrict__ flag, Consts cc) {
  const int t = threadIdx.x;
  const int tx = t & 31;
  const int ty = t >> 5;                       // 0..7
  // bijective chunked XCD swizzle: 2048 wgs, 8 XCDs, 256 wgs (16 z-slices) each
  const int wg = blockIdx.x;
  const int id = ((wg & 7) << 8) | (wg >> 3);
  const int z = id >> 4;                       // 0..127
  const int y = ((id & 15) << 3) | ty;         // 0..127
  const int x0 = tx << 2;
  const int idx = (z * DD + y) * DD + x0;
  const int nn = n * D3;

  const float4 xc4 = *(const float4*)(xg + nn + idx);
  const float4 yc4 = *(const float4*)(yg + nn + idx);
  const float4 zc4 = *(const float4*)(zg + nn + idx);
  const float4 vx4 = *(const float4*)(vnx + idx);
  const float4 vy4 = *(const float4*)(vny + idx);
  const float4 vz4 = *(const float4*)(vnz + idx);
  const float4 mk4 = *(const float4*)(maskn + idx);

  float pxc[4] = {xc4.x, xc4.y, xc4.z, xc4.w};
  float pyc[4] = {yc4.x, yc4.y, yc4.z, yc4.w};
  float pzc[4] = {zc4.x, zc4.y, zc4.z, zc4.w};
  float vxc[4] = {vx4.x, vx4.y, vx4.z, vx4.w};
  float vyc[4] = {vy4.x, vy4.y, vy4.z, vy4.w};
  float vzc[4] = {vz4.x, vz4.y, vz4.z, vz4.w};
  float mkc[4] = {mk4.x, mk4.y, mk4.z, mk4.w};

  float fxA[4] = {0.f, 0.f, 0.f, 0.f};
  float fyA[4] = {0.f, 0.f, 0.f, 0.f};
  float fzA[4] = {0.f, 0.f, 0.f, 0.f};

  if (*flag == 0u) {
    const int laneL = (t & 32) | ((tx + 31) & 31);
    const int laneR = (t & 32) | ((tx + 1) & 31);
    const float* __restrict__ Q0[6] = {xg, yg, zg, v0x, v0y, v0z};
    const float* __restrict__ Q1[6] = {xg + D3, yg + D3, zg + D3, v1x, v1y, v1z};

    auto compute_row = [&](const float4 (&Bf)[6]) {
      float lo[6], hi[6];
#pragma unroll
      for (int f = 0; f < 6; ++f) {
        lo[f] = __shfl(Bf[f].w, laneL, 64);
        hi[f] = __shfl(Bf[f].x, laneR, 64);
      }
#pragma unroll
      for (int i = 0; i < 4; ++i) {
#pragma unroll
        for (int ox = 0; ox < 3; ++ox) {
          const int u = i + ox - 1;   // -1..4, compile-time after unroll
          const float wx  = (u < 0) ? lo[0] : ((u > 3) ? hi[0] : f4c(Bf[0], u));
          const float wy  = (u < 0) ? lo[1] : ((u > 3) ? hi[1] : f4c(Bf[1], u));
          const float wz  = (u < 0) ? lo[2] : ((u > 3) ? hi[2] : f4c(Bf[2], u));
          const float wvx = (u < 0) ? lo[3] : ((u > 3) ? hi[3] : f4c(Bf[3], u));
          const float wvy = (u < 0) ? lo[4] : ((u > 3) ? hi[4] : f4c(Bf[4], u));
          const float wvz = (u < 0) ? lo[5] : ((u > 3) ? hi[5] : f4c(Bf[5], u));
          float dx = pxc[i] - wx;
          float dy = pyc[i] - wy;
          float dz = pzc[i] - wz;
          float d2 = fmaf(dx, dx, fmaf(dy, dy, dz * dz));
          float d2c = fmaxf(d2, 1e-12f);
          float r = __builtin_amdgcn_rsqf(d2c);
          float dist = d2c * r;
          float inv = fminf(r, 1.0e4f);
          float dvx = vxc[i] - wvx;
          float dvy = vyc[i] - wvy;
          float dvz = vzc[i] - wvz;
          float dvn = fmaf(dvx, dx, fmaf(dvy, dy, dvz * dz)) * inv;
          float coef = (dist < cc.ps) ? (fmaf(cc.kn, dist - cc.ps, cc.eta * dvn) * inv) : 0.0f;
          fxA[i] = fmaf(coef, dx, fxA[i]);
          fyA[i] = fmaf(coef, dy, fyA[i]);
          fzA[i] = fmaf(coef, dz, fzA[i]);
        }
      }
    };

    float4 A[6], B[6];
    {
      const int rb0 = (((z + DM) & DM) * DD + ((y + DM) & DM)) * DD + x0;
#pragma unroll
      for (int f = 0; f < 6; ++f) A[f] = *(const float4*)(Q0[f] + rb0);
    }

#pragma unroll 1
    for (int k = 0; k < 9; ++k) {
      const int iz = (k * 11) >> 5;            // k/3 for k in [0,8]
      const int iy = k - iz * 3;
      const int rb = (((z + iz + DM) & DM) * DD + ((y + iy + DM) & DM)) * DD + x0;
#pragma unroll
      for (int f = 0; f < 6; ++f) B[f] = *(const float4*)(Q1[f] + rb);
      compute_row(A);                          // layer-0 rows of pair k
      const int k1 = (k < 8) ? k + 1 : 8;
      const int iz1 = (k1 * 11) >> 5;
      const int iy1 = k1 - iz1 * 3;
      const int rb1 = (((z + iz1 + DM) & DM) * DD + ((y + iy1 + DM) & DM)) * DD + x0;
#pragma unroll
      for (int f = 0; f < 6; ++f) A[f] = *(const float4*)(Q0[f] + rb1);
      compute_row(B);                          // layer-1 rows of pair k
    }
  } else {
#pragma unroll
    for (int i = 0; i < 4; ++i) {
      collide<2>(x0 + i, y, z, xg, yg, zg, v0x, v0y, v0z, v1x, v1y, v1z,
                 pxc[i], pyc[i], pzc[i], vxc[i], vyc[i], vzc[i],
                 fxA[i], fyA[i], fzA[i], cc);
    }
  }

  float4 ox4, oy4, oz4;
#pragma unroll
  for (int i = 0; i < 4; ++i) {
    const float fxb = bforce(pxc[i], vxc[i], mkc[i], cc);
    const float fyb = bforce(pyc[i], vyc[i], mkc[i], cc);
    const float fzb = bforce(pzc[i], vzc[i], mkc[i], cc);
    const float s = cc.dtpm * mkc[i];
    (&ox4.x)[i] = vxc[i] + s * (fxb - fxA[i]);
    (&oy4.x)[i] = vyc[i] + s * (fyb - fyA[i]);
    (&oz4.x)[i] = vzc[i] + s * ((cc.grav - fzA[i]) + fzb);
  }
  *(float4*)(outx + idx) = ox4;
  *(float4*)(outy + idx) = oy4;
  *(float4*)(outz + idx) = oz4;
}

}  // namespace

extern "C" void kernel_launch(void* const* d_in, const int* in_sizes, int n_in,
                              void* d_out, int out_size, void* d_ws, size_t ws_size,
                              hipStream_t stream) {
  const float* xg = (const float*)d_in[0];
  const float* yg = (const float*)d_in[1];
  const float* zg = (const float*)d_in[2];
  const float* vx = (const float*)d_in[3];
  const float* vy = (const float*)d_in[4];
  const float* vz = (const float*)d_in[5];
  const float* mk = (const float*)d_in[6];
  float* out = (float*)d_out;
  unsigned* flag = (unsigned*)d_ws;

  const double PSd = 0.1, CELLd = 0.1, KNd = 6.0e6;
  const double ALPHA = -log(0.5) / 3.141592653589793;
  const double GAMMA = ALPHA / sqrt(ALPHA * ALPHA + 1.0);
  const double PMd = 4.0 / 3.0 * 3.1415 * (0.1 * 0.1 * 0.1) * 2700.0;
  const double ETAd = 2.0 * GAMMA * sqrt(KNd * PMd);

  Consts cc;
  cc.kn = (float)KNd;
  cc.ps = (float)PSd;
  cc.eta = (float)ETAd;
  cc.dtpm = (float)(1e-4 / PMd);
  cc.grav = (float)(-9.8 * PMd);
  cc.lo_hi = (float)(1.5 * PSd);
  cc.hi_th = (float)(DD * CELLd - 0.5 * PSd - CELLd);
  cc.dcell = (float)(DD * CELLd);
  cc.cell = (float)CELLd;
  cc.hps = (float)(0.5 * PSd);

  hipMemsetAsync(d_ws, 0, sizeof(unsigned), stream);
  checker<<<(2 * D3) / 256, 256, 0, stream>>>(xg, yg, zg, flag, cc.cell);

  dim3 blk(256, 1, 1), grd(2048, 1, 1);
  // Pass n=0: neighbor velocities = original inputs (both layers); own = input layer 0.
  dem_pass<<<grd, blk, 0, stream>>>(
      0, xg, yg, zg,
      vx, vy, vz,
      vx + D3, vy + D3, vz + D3,
      vx, vy, vz,
      mk,
      out, out + 2 * D3, out + 4 * D3,
      flag, cc);
  // Pass n=1: m=0 source is the UPDATED layer 0 (just written to out).
  dem_pass<<<grd, blk, 0, stream>>>(
      1, xg, yg, zg,
      out, out + 2 * D3, out + 4 * D3,
      vx + D3, vy + D3, vz + D3,
      vx + D3, vy + D3, vz + D3,
      mk + D3,
      out + D3, out + 3 * D3, out + 5 * D3,
      flag, cc);
}